// Round 7
// baseline (63.841 us; speedup 1.0000x reference)
//
#include <hip/hip_runtime.h>
#include <math.h>

#define NPOINTS 32768
#define NPRIMS  2048
#define BLK     256
#define PPT     2                    // points per thread
#define PTS_BLK (BLK * PPT)          // 512 points per block
#define PBLK    (NPOINTS / PTS_BLK)  // 64 point-blocks
#define NSPLIT  16                   // primitive splits (grid.y)

typedef float v2f __attribute__((ext_vector_type(2)));

// 64-byte packed record for a pair of primitives (SoA-in-pairs):
//  q0 = (mux0, mux1, muy0, muy1)
//  q1 = (muz0, muz1, amp0, amp1)
//  q2 = (gx0,  gx1,  gy0,  gy1 )   g = -0.5*log2(e)/s^2
//  q3 = (gz0,  gz1,  ph0,  ph1 )   ph in revolutions (phase/2pi)
struct PrimPair { float4 q0, q1, q2, q3; };

// Robust scalar-frequency decode (2400000000 in any plausible encoding).
__device__ __forceinline__ float read_freq(const void* p) {
    const unsigned* w = (const unsigned*)p;
    unsigned lo = w[0];
    float ff = __uint_as_float(lo);
    if (ff >= 1.0e5f && ff <= 1.0e13f) return ff;       // float32
    if (lo != 0u) return (float)lo;                      // int32-wrap / int64 lo
    double d = *(const double*)p;                        // lo==0 -> 8-byte dtype
    if (d >= 1.0e5 && d <= 1.0e13) return (float)d;      // float64
    unsigned long long v = ((unsigned long long)w[1] << 32) | lo;
    return (float)v;                                     // int64 (hi-word path)
}

__global__ __launch_bounds__(BLK) void prep_kernel(
        const float* __restrict__ pos,
        const float* __restrict__ scl,
        const float* __restrict__ amp,
        const float* __restrict__ ph,
        PrimPair* __restrict__ pp) {
    int j = blockIdx.x * blockDim.x + threadIdx.x;
    if (j >= NPRIMS / 2) return;
    const float KE     = -0.72134752044448169f;   // -0.5*log2(e)
    const float INV2PI =  0.15915494309189535f;
    int p0 = 2 * j, p1 = 2 * j + 1;
    float s0x = scl[3*p0+0], s0y = scl[3*p0+1], s0z = scl[3*p0+2];
    float s1x = scl[3*p1+0], s1y = scl[3*p1+1], s1z = scl[3*p1+2];
    PrimPair P;
    P.q0 = make_float4(pos[3*p0+0], pos[3*p1+0], pos[3*p0+1], pos[3*p1+1]);
    P.q1 = make_float4(pos[3*p0+2], pos[3*p1+2], amp[p0], amp[p1]);
    P.q2 = make_float4(KE / (s0x*s0x), KE / (s1x*s1x), KE / (s0y*s0y), KE / (s1y*s1y));
    P.q3 = make_float4(KE / (s0z*s0z), KE / (s1z*s1z), ph[p0] * INV2PI, ph[p1] * INV2PI);
    pp[j] = P;
}

// Packed sincos(2*pi*t) via rndne range-reduce to v in [-0.5,0.5] and
// Taylor-13/14 polynomials in w=v^2 (edge error 2.1e-5 / 4.8e-6).
__device__ __forceinline__ void pk_sincos_rev(v2f tp, v2f& s, v2f& c) {
    const v2f S1 = {-41.34170224039976f, -41.34170224039976f};
    const v2f S2 = { 81.60524927607504f,  81.60524927607504f};
    const v2f S3 = {-76.70585975306136f, -76.70585975306136f};
    const v2f S4 = { 42.05869394489765f,  42.05869394489765f};
    const v2f S5 = {-15.094642576822123f,-15.094642576822123f};
    const v2f S6 = {  3.8199525848482824f, 3.8199525848482824f};
    const v2f S0 = {  6.283185307179586f,  6.283185307179586f};
    const v2f C1 = {-19.739208802178716f,-19.739208802178716f};
    const v2f C2 = { 64.93939402266829f,  64.93939402266829f};
    const v2f C3 = {-85.45681720669372f, -85.45681720669372f};
    const v2f C4 = { 60.24464137187665f,  60.24464137187665f};
    const v2f C5 = {-26.426256783358706f,-26.426256783358706f};
    const v2f C6 = {  7.903536371318467f,  7.903536371318467f};
    const v2f C7 = { -1.714370232222585f, -1.714370232222585f};
    const v2f ONE = {1.0f, 1.0f};

    v2f n  = {__builtin_rintf(tp.x), __builtin_rintf(tp.y)};
    v2f v  = tp - n;
    v2f w  = v * v;
    v2f ps = __builtin_elementwise_fma(w, S6, S5);
    ps = __builtin_elementwise_fma(w, ps, S4);
    ps = __builtin_elementwise_fma(w, ps, S3);
    ps = __builtin_elementwise_fma(w, ps, S2);
    ps = __builtin_elementwise_fma(w, ps, S1);
    ps = __builtin_elementwise_fma(w, ps, S0);
    s  = v * ps;
    v2f pc = __builtin_elementwise_fma(w, C7, C6);
    pc = __builtin_elementwise_fma(w, pc, C5);
    pc = __builtin_elementwise_fma(w, pc, C4);
    pc = __builtin_elementwise_fma(w, pc, C3);
    pc = __builtin_elementwise_fma(w, pc, C2);
    pc = __builtin_elementwise_fma(w, pc, C1);
    c  = __builtin_elementwise_fma(w, pc, ONE);
}

// One point vs one primitive-pair.
__device__ __forceinline__ void eval_pair(const PrimPair& P,
                                          v2f xx, v2f yy, v2f zz, v2f kr2,
                                          v2f& re, v2f& im) {
    v2f mux = {P.q0.x, P.q0.y}, muy = {P.q0.z, P.q0.w};
    v2f muz = {P.q1.x, P.q1.y}, am2 = {P.q1.z, P.q1.w};
    v2f gx  = {P.q2.x, P.q2.y}, gy  = {P.q2.z, P.q2.w};
    v2f gz  = {P.q3.x, P.q3.y}, ph2 = {P.q3.z, P.q3.w};

    v2f dx = xx - mux, dy = yy - muy, dz = zz - muz;
    v2f t0 = dx * dx, t1 = dy * dy, t2 = dz * dz;
    v2f e  = t0 * gx + t1 * gy + t2 * gz;          // <= 0 (pk_fma chain)
    v2f d2 = t0 + t1 + t2;
    d2 = __builtin_elementwise_max(d2, (v2f){1e-12f, 1e-12f});

    v2f r2 = {__builtin_amdgcn_sqrtf(d2.x), __builtin_amdgcn_sqrtf(d2.y)};
    v2f ex = {__builtin_amdgcn_exp2f(e.x),  __builtin_amdgcn_exp2f(e.y)};
    v2f w2 = am2 * ex;
    v2f tp = __builtin_elementwise_fma(kr2, r2, ph2);   // revolutions
    v2f s2, c2;
    pk_sincos_rev(tp, s2, c2);
    re = __builtin_elementwise_fma(w2, c2, re);
    im = __builtin_elementwise_fma(w2, s2, im);
}

// Each block: 512 points (2/thread) x (NPRIMS/NSPLIT = 128) prims = 64 pairs.
// Prim records via wave-uniform s_load with 1-deep explicit prefetch.
__global__ __launch_bounds__(BLK) void field_kernel(
        const float* __restrict__ qp,
        const PrimPair* __restrict__ pp,
        const void* __restrict__ freq_p,
        float2* __restrict__ part) {
    const int n0 = blockIdx.x * PTS_BLK + threadIdx.x;
    const int n1 = n0 + BLK;
    const float kr = read_freq(freq_p) / 299792458.0f;   // cycles per metre
    const v2f kr2 = {kr, kr};

    const v2f xxa = {qp[3*n0+0], qp[3*n0+0]}, yya = {qp[3*n0+1], qp[3*n0+1]},
              zza = {qp[3*n0+2], qp[3*n0+2]};
    const v2f xxb = {qp[3*n1+0], qp[3*n1+0]}, yyb = {qp[3*n1+1], qp[3*n1+1]},
              zzb = {qp[3*n1+2], qp[3*n1+2]};

    constexpr int PAIRS = (NPRIMS / NSPLIT) / 2;   // 64 (power of two)
    const int base = blockIdx.y * PAIRS;

    v2f reA = {0.0f, 0.0f}, imA = {0.0f, 0.0f};
    v2f reB = {0.0f, 0.0f}, imB = {0.0f, 0.0f};

    PrimPair cur = pp[base];
    for (int j = 0; j < PAIRS; ++j) {
        PrimPair nxt = pp[base + ((j + 1) & (PAIRS - 1))];   // prefetch (wraps)
        eval_pair(cur, xxa, yya, zza, kr2, reA, imA);
        eval_pair(cur, xxb, yyb, zzb, kr2, reB, imB);
        cur = nxt;
    }

    part[(size_t)blockIdx.y * NPOINTS + n0] = make_float2(reA.x + reA.y, imA.x + imA.y);
    part[(size_t)blockIdx.y * NPOINTS + n1] = make_float2(reB.x + reB.y, imB.x + imB.y);
}

__global__ __launch_bounds__(BLK) void reduce_kernel(const float2* __restrict__ part,
                                                     float* __restrict__ out) {
    int n = blockIdx.x * blockDim.x + threadIdx.x;
    float re = 0.0f, im = 0.0f;
    #pragma unroll
    for (int s = 0; s < NSPLIT; ++s) {
        float2 v = part[(size_t)s * NPOINTS + n];
        re += v.x; im += v.y;
    }
    out[n]           = re;   // planar: real block then imag block
    out[NPOINTS + n] = im;
}

// Fallback (tiny workspace): LDS kernel, single pass, direct planar output.
__global__ __launch_bounds__(BLK) void field_fallback(
        const float* __restrict__ qp,
        const float* __restrict__ pos,
        const float* __restrict__ scl,
        const float* __restrict__ amp,
        const float* __restrict__ ph,
        const void*  __restrict__ freq_p,
        float*       __restrict__ out) {
    __shared__ float4 sA[128];
    __shared__ float4 sB[128];
    const int n = blockIdx.x * BLK + threadIdx.x;
    const float x = qp[3*n+0], y = qp[3*n+1], z = qp[3*n+2];
    const float kr = read_freq(freq_p) / 299792458.0f;
    const float KE = -0.72134752044448169f, INV2PI = 0.15915494309189535f;
    float re = 0.0f, im = 0.0f;
    for (int tile = 0; tile < NPRIMS / 128; ++tile) {
        __syncthreads();
        if (threadIdx.x < 128) {
            int p = tile * 128 + threadIdx.x;
            float sx = scl[3*p+0], sy = scl[3*p+1], sz = scl[3*p+2];
            sA[threadIdx.x] = make_float4(pos[3*p+0], pos[3*p+1], pos[3*p+2], amp[p]);
            sB[threadIdx.x] = make_float4(KE/(sx*sx), KE/(sy*sy), KE/(sz*sz), ph[p]*INV2PI);
        }
        __syncthreads();
        #pragma unroll 8
        for (int p = 0; p < 128; ++p) {
            float4 a = sA[p];
            float4 b = sB[p];
            float dx = x - a.x, dy = y - a.y, dz = z - a.z;
            float t0 = dx*dx, t1 = dy*dy, t2 = dz*dz;
            float e  = fmaf(t0, b.x, fmaf(t1, b.y, t2 * b.z));
            float d2 = t0 + t1 + t2;
            float r  = __builtin_amdgcn_sqrtf(fmaxf(d2, 1e-12f));
            float w  = a.w * __builtin_amdgcn_exp2f(e);
            float tp = __builtin_amdgcn_fractf(fmaf(kr, r, b.w));
            float s  = __builtin_amdgcn_sinf(tp);
            float c  = __builtin_amdgcn_cosf(tp);
            re = fmaf(w, c, re);
            im = fmaf(w, s, im);
        }
    }
    out[n]           = re;
    out[NPOINTS + n] = im;
}

extern "C" void kernel_launch(void* const* d_in, const int* in_sizes, int n_in,
                              void* d_out, int out_size, void* d_ws, size_t ws_size,
                              hipStream_t stream) {
    const float* qp  = (const float*)d_in[0];
    const float* pos = (const float*)d_in[1];
    const float* scl = (const float*)d_in[2];
    const float* amp = (const float*)d_in[3];
    const float* ph  = (const float*)d_in[4];
    const void*  fq  = d_in[5];
    float* out = (float*)d_out;

    const size_t packed_bytes = (size_t)(NPRIMS / 2) * sizeof(PrimPair);   // 64 KB
    const size_t part_bytes   = (size_t)NSPLIT * NPOINTS * sizeof(float2); // 4 MB

    if (ws_size >= packed_bytes + part_bytes) {
        PrimPair* pp   = (PrimPair*)d_ws;
        float2*   part = (float2*)((char*)d_ws + packed_bytes);
        prep_kernel<<<dim3((NPRIMS/2 + BLK - 1) / BLK), dim3(BLK), 0, stream>>>(pos, scl, amp, ph, pp);
        field_kernel<<<dim3(PBLK, NSPLIT), dim3(BLK), 0, stream>>>(qp, pp, fq, part);
        reduce_kernel<<<dim3(NPOINTS / BLK), dim3(BLK), 0, stream>>>(part, out);
    } else {
        field_fallback<<<dim3(NPOINTS / BLK), dim3(BLK), 0, stream>>>(qp, pos, scl, amp, ph, fq, out);
    }
}

// Round 8
// 49.792 us; speedup vs baseline: 1.2822x; 1.2822x over previous
//
#include <hip/hip_runtime.h>
#include <math.h>

#define NPOINTS 32768
#define NPRIMS  2048
#define BLK     256

typedef float v2f __attribute__((ext_vector_type(2)));

// 64-byte packed record for a pair of primitives (SoA-in-pairs):
//  q0 = (mux0, mux1, muy0, muy1)
//  q1 = (muz0, muz1, amp0, amp1)
//  q2 = (gx0,  gx1,  gy0,  gy1 )   g = -0.5*log2(e)/s^2
//  q3 = (gz0,  gz1,  ph0,  ph1 )   ph in revolutions (phase/2pi)
struct PrimPair { float4 q0, q1, q2, q3; };

// Robust scalar-frequency decode (2400000000 in any plausible encoding).
__device__ __forceinline__ float read_freq(const void* p) {
    const unsigned* w = (const unsigned*)p;
    unsigned lo = w[0];
    float ff = __uint_as_float(lo);
    if (ff >= 1.0e5f && ff <= 1.0e13f) return ff;       // float32
    if (lo != 0u) return (float)lo;                      // int32-wrap / int64 lo
    double d = *(const double*)p;                        // lo==0 -> 8-byte dtype
    if (d >= 1.0e5 && d <= 1.0e13) return (float)d;      // float64
    unsigned long long v = ((unsigned long long)w[1] << 32) | lo;
    return (float)v;                                     // int64 (hi-word path)
}

__global__ __launch_bounds__(BLK) void prep_kernel(
        const float* __restrict__ pos,
        const float* __restrict__ scl,
        const float* __restrict__ amp,
        const float* __restrict__ ph,
        PrimPair* __restrict__ pp) {
    int j = blockIdx.x * blockDim.x + threadIdx.x;
    if (j >= NPRIMS / 2) return;
    const float KE     = -0.72134752044448169f;   // -0.5*log2(e)
    const float INV2PI =  0.15915494309189535f;
    int p0 = 2 * j, p1 = 2 * j + 1;
    float s0x = scl[3*p0+0], s0y = scl[3*p0+1], s0z = scl[3*p0+2];
    float s1x = scl[3*p1+0], s1y = scl[3*p1+1], s1z = scl[3*p1+2];
    PrimPair P;
    P.q0 = make_float4(pos[3*p0+0], pos[3*p1+0], pos[3*p0+1], pos[3*p1+1]);
    P.q1 = make_float4(pos[3*p0+2], pos[3*p1+2], amp[p0], amp[p1]);
    P.q2 = make_float4(KE / (s0x*s0x), KE / (s1x*s1x), KE / (s0y*s0y), KE / (s1y*s1y));
    P.q3 = make_float4(KE / (s0z*s0z), KE / (s1z*s1z), ph[p0] * INV2PI, ph[p1] * INV2PI);
    pp[j] = P;
}

// One point vs one primitive-pair (R6's verified hw-trig math, unchanged).
__device__ __forceinline__ void eval_pair(const PrimPair& P,
                                          v2f xx, v2f yy, v2f zz, v2f kr2,
                                          v2f& re, v2f& im) {
    v2f mux = {P.q0.x, P.q0.y}, muy = {P.q0.z, P.q0.w};
    v2f muz = {P.q1.x, P.q1.y}, am2 = {P.q1.z, P.q1.w};
    v2f gx  = {P.q2.x, P.q2.y}, gy  = {P.q2.z, P.q2.w};
    v2f gz  = {P.q3.x, P.q3.y}, ph2 = {P.q3.z, P.q3.w};

    v2f dx = xx - mux, dy = yy - muy, dz = zz - muz;
    v2f t0 = dx * dx, t1 = dy * dy, t2 = dz * dz;
    v2f e  = t0 * gx + t1 * gy + t2 * gz;          // <= 0 (pk_fma chain)
    v2f d2 = t0 + t1 + t2;
    d2 = __builtin_elementwise_max(d2, (v2f){1e-12f, 1e-12f});

    v2f r2 = {__builtin_amdgcn_sqrtf(d2.x), __builtin_amdgcn_sqrtf(d2.y)};
    v2f ex = {__builtin_amdgcn_exp2f(e.x),  __builtin_amdgcn_exp2f(e.y)};
    v2f w2 = am2 * ex;
    v2f tp = __builtin_elementwise_fma(kr2, r2, ph2);   // revolutions
    float f0 = __builtin_amdgcn_fractf(tp.x);
    float f1 = __builtin_amdgcn_fractf(tp.y);
    v2f s2 = {__builtin_amdgcn_sinf(f0), __builtin_amdgcn_sinf(f1)};
    v2f c2 = {__builtin_amdgcn_cosf(f0), __builtin_amdgcn_cosf(f1)};
    re = __builtin_elementwise_fma(w2, c2, re);
    im = __builtin_elementwise_fma(w2, s2, im);
}

// Each block: BLK*PPT points x (NPRIMS/NSPLIT) prims. Prim records arrive via
// wave-uniform s_load; PPT points per thread amortize each 64B record.
template <int NSPLIT, int PPT>
__global__ __launch_bounds__(BLK) void field_kernel(
        const float* __restrict__ qp,
        const PrimPair* __restrict__ pp,
        const void* __restrict__ freq_p,
        float2* __restrict__ part) {
    constexpr int PAIRS = (NPRIMS / NSPLIT) / 2;
    const int nb = blockIdx.x * (BLK * PPT) + threadIdx.x;
    const float kr = read_freq(freq_p) / 299792458.0f;   // cycles per metre
    const v2f kr2 = {kr, kr};

    v2f xx[PPT], yy[PPT], zz[PPT], re[PPT], im[PPT];
    #pragma unroll
    for (int i = 0; i < PPT; ++i) {
        int n = nb + i * BLK;
        xx[i] = (v2f){qp[3*n+0], qp[3*n+0]};
        yy[i] = (v2f){qp[3*n+1], qp[3*n+1]};
        zz[i] = (v2f){qp[3*n+2], qp[3*n+2]};
        re[i] = (v2f){0.0f, 0.0f};
        im[i] = (v2f){0.0f, 0.0f};
    }

    const int base = blockIdx.y * PAIRS;
    #pragma unroll 4
    for (int j = 0; j < PAIRS; ++j) {
        PrimPair P = pp[base + j];                 // wave-uniform -> s_load
        #pragma unroll
        for (int i = 0; i < PPT; ++i)
            eval_pair(P, xx[i], yy[i], zz[i], kr2, re[i], im[i]);
    }

    #pragma unroll
    for (int i = 0; i < PPT; ++i) {
        int n = nb + i * BLK;
        part[(size_t)blockIdx.y * NPOINTS + n] =
            make_float2(re[i].x + re[i].y, im[i].x + im[i].y);
    }
}

template <int NSPLIT>
__global__ __launch_bounds__(BLK) void reduce_kernel(const float2* __restrict__ part,
                                                     float* __restrict__ out) {
    int n = blockIdx.x * blockDim.x + threadIdx.x;
    float re = 0.0f, im = 0.0f;
    #pragma unroll
    for (int s = 0; s < NSPLIT; ++s) {
        float2 v = part[(size_t)s * NPOINTS + n];
        re += v.x; im += v.y;
    }
    out[n]           = re;   // planar: real block then imag block
    out[NPOINTS + n] = im;
}

// Fallback (tiny workspace): LDS kernel, single pass, direct planar output.
__global__ __launch_bounds__(BLK) void field_fallback(
        const float* __restrict__ qp,
        const float* __restrict__ pos,
        const float* __restrict__ scl,
        const float* __restrict__ amp,
        const float* __restrict__ ph,
        const void*  __restrict__ freq_p,
        float*       __restrict__ out) {
    __shared__ float4 sA[128];
    __shared__ float4 sB[128];
    const int n = blockIdx.x * BLK + threadIdx.x;
    const float x = qp[3*n+0], y = qp[3*n+1], z = qp[3*n+2];
    const float kr = read_freq(freq_p) / 299792458.0f;
    const float KE = -0.72134752044448169f, INV2PI = 0.15915494309189535f;
    float re = 0.0f, im = 0.0f;
    for (int tile = 0; tile < NPRIMS / 128; ++tile) {
        __syncthreads();
        if (threadIdx.x < 128) {
            int p = tile * 128 + threadIdx.x;
            float sx = scl[3*p+0], sy = scl[3*p+1], sz = scl[3*p+2];
            sA[threadIdx.x] = make_float4(pos[3*p+0], pos[3*p+1], pos[3*p+2], amp[p]);
            sB[threadIdx.x] = make_float4(KE/(sx*sx), KE/(sy*sy), KE/(sz*sz), ph[p]*INV2PI);
        }
        __syncthreads();
        #pragma unroll 8
        for (int p = 0; p < 128; ++p) {
            float4 a = sA[p];
            float4 b = sB[p];
            float dx = x - a.x, dy = y - a.y, dz = z - a.z;
            float t0 = dx*dx, t1 = dy*dy, t2 = dz*dz;
            float e  = fmaf(t0, b.x, fmaf(t1, b.y, t2 * b.z));
            float d2 = t0 + t1 + t2;
            float r  = __builtin_amdgcn_sqrtf(fmaxf(d2, 1e-12f));
            float w  = a.w * __builtin_amdgcn_exp2f(e);
            float tp = __builtin_amdgcn_fractf(fmaf(kr, r, b.w));
            float s  = __builtin_amdgcn_sinf(tp);
            float c  = __builtin_amdgcn_cosf(tp);
            re = fmaf(w, c, re);
            im = fmaf(w, s, im);
        }
    }
    out[n]           = re;
    out[NPOINTS + n] = im;
}

extern "C" void kernel_launch(void* const* d_in, const int* in_sizes, int n_in,
                              void* d_out, int out_size, void* d_ws, size_t ws_size,
                              hipStream_t stream) {
    const float* qp  = (const float*)d_in[0];
    const float* pos = (const float*)d_in[1];
    const float* scl = (const float*)d_in[2];
    const float* amp = (const float*)d_in[3];
    const float* ph  = (const float*)d_in[4];
    const void*  fq  = d_in[5];
    float* out = (float*)d_out;

    const size_t packed_bytes = (size_t)(NPRIMS / 2) * sizeof(PrimPair);   // 64 KB
    const size_t ps32 = packed_bytes + (size_t)32 * NPOINTS * sizeof(float2); // +8 MB
    const size_t ps16 = packed_bytes + (size_t)16 * NPOINTS * sizeof(float2); // +4 MB

    if (ws_size >= ps32) {
        // 2048 blocks (full machine), 2 points/thread, 32 prim-pairs per block
        PrimPair* pp   = (PrimPair*)d_ws;
        float2*   part = (float2*)((char*)d_ws + packed_bytes);
        prep_kernel<<<dim3((NPRIMS/2 + BLK - 1) / BLK), dim3(BLK), 0, stream>>>(pos, scl, amp, ph, pp);
        field_kernel<32, 2><<<dim3(NPOINTS / (BLK * 2), 32), dim3(BLK), 0, stream>>>(qp, pp, fq, part);
        reduce_kernel<32><<<dim3(NPOINTS / BLK), dim3(BLK), 0, stream>>>(part, out);
    } else if (ws_size >= ps16) {
        // exact round-6 configuration (known 42.8 us)
        PrimPair* pp   = (PrimPair*)d_ws;
        float2*   part = (float2*)((char*)d_ws + packed_bytes);
        prep_kernel<<<dim3((NPRIMS/2 + BLK - 1) / BLK), dim3(BLK), 0, stream>>>(pos, scl, amp, ph, pp);
        field_kernel<16, 1><<<dim3(NPOINTS / BLK, 16), dim3(BLK), 0, stream>>>(qp, pp, fq, part);
        reduce_kernel<16><<<dim3(NPOINTS / BLK), dim3(BLK), 0, stream>>>(part, out);
    } else {
        field_fallback<<<dim3(NPOINTS / BLK), dim3(BLK), 0, stream>>>(qp, pos, scl, amp, ph, fq, out);
    }
}